// Round 3
// baseline (52.894 us; speedup 1.0000x reference)
//
#include <hip/hip_runtime.h>
#include <math.h>

#define B_SZ 16
#define K_PTS 4096
#define ALPHA 1.1f

#define ICH 1024             // i-points covered per block
#define IPT 4                // i-points per thread (ILP)
#define THR 256

#define BIGF 3.0e38f

__device__ __forceinline__ void insert3(float d, float& m0, float& m1, float& m2) {
    // branchless sorted insert, keeps 3 smallest (m0 <= m1 <= m2)
    m2 = __builtin_amdgcn_fmed3f(d, m1, m2);
    m1 = __builtin_amdgcn_fmed3f(d, m0, m1);
    m0 = fminf(d, m0);
}

// Partial top-3 of shifted distance d' = -2<xi,xj> + ||xj||^2 over one j-tile.
// grid: ((K_PTS/ICH)*JSV, B_SZ), block: 256. ws[((b*JSV+js)*3+s)*K_PTS + i].
template <int JSV>
__global__ __launch_bounds__(256) void sor_partial_t(
    const float* __restrict__ x, float* __restrict__ ws)
{
    constexpr int JTT = K_PTS / JSV;
    __shared__ float4 pts[JTT];
    const int b  = blockIdx.y;
    const int js = blockIdx.x & (JSV - 1);
    const int ic = blockIdx.x / JSV;
    const int j0 = js * JTT;
    const float* xb = x + (size_t)b * K_PTS * 3;

    for (int p = threadIdx.x; p < JTT; p += THR) {
        float a0 = xb[(j0 + p) * 3 + 0];
        float a1 = xb[(j0 + p) * 3 + 1];
        float a2 = xb[(j0 + p) * 3 + 2];
        pts[p] = make_float4(a0, a1, a2, a0 * a0 + a1 * a1 + a2 * a2);
    }
    __syncthreads();

    const int ibase = ic * ICH + threadIdx.x;
    float x2[IPT], y2[IPT], z2[IPT];          // -2 * xi
    float m0[IPT], m1[IPT], m2[IPT];
    #pragma unroll
    for (int k = 0; k < IPT; ++k) {
        const int i = ibase + k * THR;
        x2[k] = -2.0f * xb[i * 3 + 0];
        y2[k] = -2.0f * xb[i * 3 + 1];
        z2[k] = -2.0f * xb[i * 3 + 2];
        m0[k] = BIGF; m1[k] = BIGF; m2[k] = BIGF;
    }

    // 1-ahead software pipeline on the broadcast LDS read.
    float4 cur = pts[0];
    #pragma unroll 4
    for (int j = 0; j < JTT; ++j) {
        const float4 nxt = pts[(j + 1) & (JTT - 1)];
        #pragma unroll
        for (int k = 0; k < IPT; ++k) {
            float t = fmaf(z2[k], cur.z, cur.w);
            t = fmaf(y2[k], cur.y, t);
            float d = fmaf(x2[k], cur.x, t);   // d' = -2 dot + ||xj||^2
            insert3(d, m0[k], m1[k], m2[k]);
        }
        cur = nxt;
    }

    #pragma unroll
    for (int k = 0; k < IPT; ++k) {
        const int i = ibase + k * THR;
        float* w = ws + (size_t)((b * JSV + js) * 3) * K_PTS + i;
        w[0]          = m0[k];
        w[K_PTS]      = m1[k];
        w[2 * K_PTS]  = m2[k];
    }
}

// Merge JSV partial triples per point -> mean of 2NN distances (self dropped at m0).
template <int JSV>
__global__ __launch_bounds__(256) void sor_merge_t(
    const float* __restrict__ x, const float* __restrict__ ws,
    float* __restrict__ value)
{
    const int gid = blockIdx.x * 256 + threadIdx.x;   // 0 .. B*K-1
    const int b = gid >> 12;
    const int i = gid & (K_PTS - 1);

    float m0 = BIGF, m1 = BIGF, m2 = BIGF;
    #pragma unroll
    for (int js = 0; js < JSV; ++js) {
        #pragma unroll
        for (int s = 0; s < 3; ++s) {
            float d = ws[(size_t)((b * JSV + js) * 3 + s) * K_PTS + i];
            insert3(d, m0, m1, m2);
        }
    }
    const float a0 = x[(size_t)gid * 3 + 0];
    const float a1 = x[(size_t)gid * 3 + 1];
    const float a2 = x[(size_t)gid * 3 + 2];
    const float xx = a0 * a0 + a1 * a1 + a2 * a2;
    // un-shift: true distances are m' + ||xi||^2; m0 is self (global min).
    value[gid] = ((m1 + xx) + (m2 + xx)) * 0.5f;
}

// One block per batch: mean/std(ddof=1) -> threshold -> mask + zeroed points.
__global__ __launch_bounds__(1024) void sor_mask_kernel(
    const float* __restrict__ x, float* __restrict__ out)
{
    const int b = blockIdx.x;
    const int tid = threadIdx.x;
    float* value = out + (size_t)B_SZ * K_PTS * 3;
    float* selpc = out;

    __shared__ float red[16];
    __shared__ float sh_mean, sh_thr;

    float v[4];
    float s = 0.0f;
    #pragma unroll
    for (int k = 0; k < 4; ++k) {
        v[k] = value[b * K_PTS + tid + k * 1024];
        s += v[k];
    }
    #pragma unroll
    for (int off = 32; off > 0; off >>= 1) s += __shfl_down(s, off, 64);
    if ((tid & 63) == 0) red[tid >> 6] = s;
    __syncthreads();
    if (tid == 0) {
        float t = 0.0f;
        for (int w = 0; w < 16; ++w) t += red[w];
        sh_mean = t * (1.0f / (float)K_PTS);
    }
    __syncthreads();
    const float mean = sh_mean;

    float q = 0.0f;
    #pragma unroll
    for (int k = 0; k < 4; ++k) { float dv = v[k] - mean; q += dv * dv; }
    #pragma unroll
    for (int off = 32; off > 0; off >>= 1) q += __shfl_down(q, off, 64);
    if ((tid & 63) == 0) red[tid >> 6] = q;
    __syncthreads();
    if (tid == 0) {
        float t = 0.0f;
        for (int w = 0; w < 16; ++w) t += red[w];
        sh_thr = mean + ALPHA * sqrtf(t / (float)(K_PTS - 1));
    }
    __syncthreads();
    const float thr = sh_thr;

    #pragma unroll
    for (int k = 0; k < 4; ++k) {
        const int i = tid + k * 1024;
        const bool keep = v[k] <= thr;
        value[b * K_PTS + i] = keep ? 1.0f : 0.0f;
        const size_t base = ((size_t)b * K_PTS + i) * 3;
        float x0 = x[base + 0];
        float x1 = x[base + 1];
        float x2 = x[base + 2];
        selpc[base + 0] = keep ? x0 : 0.0f;
        selpc[base + 1] = keep ? x1 : 0.0f;
        selpc[base + 2] = keep ? x2 : 0.0f;
    }
}

// ---- Fallback (round-1 kernel) used only if d_ws is too small ----
__global__ __launch_bounds__(256) void sor_value_kernel(
    const float* __restrict__ x, float* __restrict__ value)
{
    __shared__ float4 pts[K_PTS];
    const int b = blockIdx.y;
    const float* xb = x + (size_t)b * K_PTS * 3;
    for (int p = threadIdx.x; p < K_PTS; p += 256) {
        float a0 = xb[p * 3 + 0];
        float a1 = xb[p * 3 + 1];
        float a2 = xb[p * 3 + 2];
        pts[p] = make_float4(a0, a1, a2, a0 * a0 + a1 * a1 + a2 * a2);
    }
    __syncthreads();
    const int i = blockIdx.x * 256 + threadIdx.x;
    const float4 pi = pts[i];
    float m0 = BIGF, m1 = BIGF, m2 = BIGF;
    #pragma unroll 8
    for (int j = 0; j < K_PTS; ++j) {
        float4 pj = pts[j];
        float dot = pi.x * pj.x + pi.y * pj.y + pi.z * pj.z;
        float d = (pi.w - 2.0f * dot) + pj.w;
        insert3(d, m0, m1, m2);
    }
    value[b * K_PTS + i] = 0.5f * (m1 + m2);
}

extern "C" void kernel_launch(void* const* d_in, const int* in_sizes, int n_in,
                              void* d_out, int out_size, void* d_ws, size_t ws_size,
                              hipStream_t stream)
{
    const float* x = (const float*)d_in[0];
    float* out = (float*)d_out;
    float* value = out + (size_t)B_SZ * K_PTS * 3;

    const size_t ws_js16 = (size_t)B_SZ * 16 * 3 * K_PTS * sizeof(float); // 12.6 MiB
    const size_t ws_js8  = (size_t)B_SZ *  8 * 3 * K_PTS * sizeof(float); //  6.3 MiB

    if (ws_size >= ws_js16) {
        float* ws = (float*)d_ws;
        dim3 gA((K_PTS / ICH) * 16, B_SZ);                 // (64, 16) = 1024 blocks
        sor_partial_t<16><<<gA, THR, 0, stream>>>(x, ws);
        sor_merge_t<16><<<(B_SZ * K_PTS) / 256, 256, 0, stream>>>(x, ws, value);
    } else if (ws_size >= ws_js8) {
        float* ws = (float*)d_ws;
        dim3 gA((K_PTS / ICH) * 8, B_SZ);                  // (32, 16) = 512 blocks
        sor_partial_t<8><<<gA, THR, 0, stream>>>(x, ws);
        sor_merge_t<8><<<(B_SZ * K_PTS) / 256, 256, 0, stream>>>(x, ws, value);
    } else {
        dim3 g1(K_PTS / 256, B_SZ);
        sor_value_kernel<<<g1, 256, 0, stream>>>(x, value);
    }
    sor_mask_kernel<<<B_SZ, 1024, 0, stream>>>(x, out);
}